// Round 18
// baseline (563.042 us; speedup 1.0000x reference)
//
#include <hip/hip_runtime.h>

#define NN 100000
#define NE 1600000
#define NG 1024
#define NODE_IN 163
#define SLOPE 0.01f
#define NBUK 391
#define BUKSH 8
#define EPB 8192
#define NBLK ((NE + EPB - 1) / EPB)
#define NPADC 100096
#define PLANE ((size_t)NPADC * 16)   // ushorts per feature-plane
#define BPP 25000                    // agg blocks per plane (NN/4)

typedef short s16x8 __attribute__((ext_vector_type(8)));
typedef float f32x4 __attribute__((ext_vector_type(4)));

__device__ __forceinline__ unsigned short bf16_rne(float x) {
  unsigned u = __float_as_uint(x);
  return (unsigned short)((u + 0x7FFFu + ((u >> 16) & 1u)) >> 16);
}
__device__ __forceinline__ float bf16_f32(unsigned short h) {
  return __uint_as_float(((unsigned)h) << 16);
}

// ---------------- CSR build (privatized counting sort; rounds 4-14, verified) ---------
__global__ void k_hist(const int* __restrict__ dst, int* __restrict__ bh, int E) {
  __shared__ int h[NBUK];
  for (int i = threadIdx.x; i < NBUK; i += 256) h[i] = 0;
  __syncthreads();
  int beg = blockIdx.x * EPB, end = min(E, beg + EPB);
  for (int e = beg + threadIdx.x; e < end; e += 256) atomicAdd(&h[dst[e] >> BUKSH], 1);
  __syncthreads();
  for (int i = threadIdx.x; i < NBUK; i += 256) bh[blockIdx.x * NBUK + i] = h[i];
}

__global__ void k_bucket_scan(int* __restrict__ bh, int* __restrict__ btot) {
  __shared__ int s[256];
  int bucket = blockIdx.x, tid = threadIdx.x;
  int v = (tid < NBLK) ? bh[tid * NBUK + bucket] : 0;
  s[tid] = v;
  __syncthreads();
  for (int off = 1; off < 256; off <<= 1) {
    int t = (tid >= off) ? s[tid - off] : 0;
    __syncthreads();
    s[tid] += t;
    __syncthreads();
  }
  if (tid < NBLK) bh[tid * NBUK + bucket] = s[tid] - v;
  if (tid == 255) btot[bucket] = s[255];
}

__global__ void k_btot_scan(const int* __restrict__ btot, int* __restrict__ boffs, int E) {
  __shared__ int s[512];
  int tid = threadIdx.x;
  int v = (tid < NBUK) ? btot[tid] : 0;
  s[tid] = v;
  __syncthreads();
  for (int off = 1; off < 512; off <<= 1) {
    int t = (tid >= off) ? s[tid - off] : 0;
    __syncthreads();
    s[tid] += t;
    __syncthreads();
  }
  if (tid < NBUK) boffs[tid] = s[tid] - v;
  if (tid == 0) boffs[NBUK] = E;
}

__global__ void k_scatter(const int* __restrict__ src, const int* __restrict__ dst,
                          const int* __restrict__ bh, const int* __restrict__ boffs,
                          unsigned* __restrict__ bedge, int E) {
  __shared__ int cur[NBUK];
  for (int i = threadIdx.x; i < NBUK; i += 256)
    cur[i] = boffs[i] + bh[blockIdx.x * NBUK + i];
  __syncthreads();
  int beg = blockIdx.x * EPB, end = min(E, beg + EPB);
  for (int e = beg + threadIdx.x; e < end; e += 256) {
    int d = dst[e];
    int pos = atomicAdd(&cur[d >> BUKSH], 1);
    bedge[pos] = (unsigned)src[e] | ((unsigned)(d & 255) << 17);
  }
}

__global__ void k_b2csr(const unsigned* __restrict__ bedge, const int* __restrict__ boffs,
                        int* __restrict__ offs, float* __restrict__ dis,
                        int* __restrict__ csr, int N) {
  __shared__ int lcnt[256];
  __shared__ int s[256];
  __shared__ int lcur[256];
  int b = blockIdx.x, tid = threadIdx.x;
  int beg = boffs[b], end = boffs[b + 1];
  lcnt[tid] = 0;
  __syncthreads();
  for (int e = beg + tid; e < end; e += 256) atomicAdd(&lcnt[bedge[e] >> 17], 1);
  __syncthreads();
  int v = lcnt[tid];
  s[tid] = v;
  __syncthreads();
  for (int off = 1; off < 256; off <<= 1) {
    int t = (tid >= off) ? s[tid - off] : 0;
    __syncthreads();
    s[tid] += t;
    __syncthreads();
  }
  int o = s[tid] - v;
  int node = (b << BUKSH) + tid;
  if (node <= N) offs[node] = beg + o;
  if (node < N) dis[node] = rsqrtf((float)(v + 1));
  lcur[tid] = o;
  __syncthreads();
  for (int e = beg + tid; e < end; e += 256) {
    unsigned w = bedge[e];
    int p = atomicAdd(&lcur[w >> 17], 1);
    csr[beg + p] = (int)(w & 0x1FFFFu);
  }
}

// ---------------- W pre-split: W[K][64] fp32 -> Wt_hi/lo[64][KP] bf16 (transposed) ----
__global__ void k_wsplit(const float* __restrict__ W, short* __restrict__ hi,
                         short* __restrict__ lo, int K, int KP) {
  int idx = blockIdx.x * 256 + threadIdx.x;
  if (idx >= 64 * KP) return;
  int c = idx / KP, kk = idx - c * KP;
  float v = (kk < K) ? W[(size_t)kk * 64 + c] : 0.f;
  unsigned short h = bf16_rne(v);
  hi[idx] = (short)h;
  lo[idx] = (short)bf16_rne(v - bf16_f32(h));
}

// ---------------- GEMM via MFMA split-bf16; output bf16 FEATURE PLANES ---------------
// Plane q = cols [16q,16q+16): G_q[node][16], 3.2MB each (fits an XCD L2).
template<int K, int KP>
__launch_bounds__(256)
__global__ void k_gemm(const float* __restrict__ X, const short* __restrict__ Whi,
                       const short* __restrict__ Wlo, const float* __restrict__ disv,
                       unsigned short* __restrict__ Y, int N) {
  constexpr int KC = KP / 32;
  constexpr int PA = 40;
  constexpr int PB = 40;
  __shared__ __align__(16) short sAh[2][128 * PA];
  __shared__ __align__(16) short sAl[2][128 * PA];
  __shared__ __align__(16) short sBh[2][64 * PB];
  __shared__ __align__(16) short sBl[2][64 * PB];

  const int tid = threadIdx.x;
  const int lane = tid & 63, wv = tid >> 6;
  const int l15 = lane & 15, l4 = lane >> 4;
  const int gbase = blockIdx.x << 7;

  const int arow = tid >> 1, akh = (tid & 1) << 4;
  int grow = gbase + arow;
  if (K != KP) grow = min(grow, N - 1);
  const float* xr = X + (size_t)grow * K;
  const int bcol = tid >> 2, bk8 = (tid & 3) << 3;

  float4 ra0, ra1, ra2, ra3;
  s16x8 rbh, rbl;

  auto loadA = [&](int c) {
    if (K != KP && c == KC - 1) {
      ra0 = ra1 = ra2 = ra3 = make_float4(0.f, 0.f, 0.f, 0.f);
      if (akh == 0) { ra0.x = xr[160]; ra0.y = xr[161]; ra0.z = xr[162]; }
    } else {
      const float* p = xr + c * 32 + akh;
      ra0 = *(const float4*)(p);
      ra1 = *(const float4*)(p + 4);
      ra2 = *(const float4*)(p + 8);
      ra3 = *(const float4*)(p + 12);
    }
  };
  auto loadB = [&](int c) {
    const size_t o = (size_t)bcol * KP + c * 32 + bk8;
    rbh = *(const s16x8*)(Whi + o);
    rbl = *(const s16x8*)(Wlo + o);
  };
  auto writeLDS = [&](int b) {
    short hb[16], lb[16];
    float v[16] = {ra0.x, ra0.y, ra0.z, ra0.w, ra1.x, ra1.y, ra1.z, ra1.w,
                   ra2.x, ra2.y, ra2.z, ra2.w, ra3.x, ra3.y, ra3.z, ra3.w};
    #pragma unroll
    for (int j = 0; j < 16; ++j) {
      unsigned short h = bf16_rne(v[j]);
      hb[j] = (short)h;
      lb[j] = (short)bf16_rne(v[j] - bf16_f32(h));
    }
    short* ah = sAh[b] + arow * PA + akh;
    *(s16x8*)(ah) = *(const s16x8*)(hb);
    *(s16x8*)(ah + 8) = *(const s16x8*)(hb + 8);
    short* al = sAl[b] + arow * PA + akh;
    *(s16x8*)(al) = *(const s16x8*)(lb);
    *(s16x8*)(al + 8) = *(const s16x8*)(lb + 8);
    *(s16x8*)(sBh[b] + bcol * PB + bk8) = rbh;
    *(s16x8*)(sBl[b] + bcol * PB + bk8) = rbl;
  };

  f32x4 acc[2][4];
  #pragma unroll
  for (int rt = 0; rt < 2; ++rt)
    #pragma unroll
    for (int ct = 0; ct < 4; ++ct) acc[rt][ct] = (f32x4){0.f, 0.f, 0.f, 0.f};

  loadA(0); loadB(0); writeLDS(0);
  __syncthreads();

  #pragma unroll 1
  for (int c = 0; c < KC; ++c) {
    if (c + 1 < KC) { loadA(c + 1); loadB(c + 1); }   // issue early (T14)
    const int b = c & 1;
    const int aoff0 = (wv * 32 + l15) * PA + l4 * 8;
    const int aoff1 = aoff0 + 16 * PA;
    s16x8 a0h = *(const s16x8*)(sAh[b] + aoff0);
    s16x8 a0l = *(const s16x8*)(sAl[b] + aoff0);
    s16x8 a1h = *(const s16x8*)(sAh[b] + aoff1);
    s16x8 a1l = *(const s16x8*)(sAl[b] + aoff1);
    #pragma unroll
    for (int ct = 0; ct < 4; ++ct) {
      const int boff = (ct * 16 + l15) * PB + l4 * 8;
      s16x8 bh = *(const s16x8*)(sBh[b] + boff);
      s16x8 bl = *(const s16x8*)(sBl[b] + boff);
      acc[0][ct] = __builtin_amdgcn_mfma_f32_16x16x32_bf16(a0h, bh, acc[0][ct], 0, 0, 0);
      acc[0][ct] = __builtin_amdgcn_mfma_f32_16x16x32_bf16(a0l, bh, acc[0][ct], 0, 0, 0);
      acc[0][ct] = __builtin_amdgcn_mfma_f32_16x16x32_bf16(a0h, bl, acc[0][ct], 0, 0, 0);
      acc[1][ct] = __builtin_amdgcn_mfma_f32_16x16x32_bf16(a1h, bh, acc[1][ct], 0, 0, 0);
      acc[1][ct] = __builtin_amdgcn_mfma_f32_16x16x32_bf16(a1l, bh, acc[1][ct], 0, 0, 0);
      acc[1][ct] = __builtin_amdgcn_mfma_f32_16x16x32_bf16(a1h, bl, acc[1][ct], 0, 0, 0);
    }
    if (c + 1 < KC) { writeLDS((c + 1) & 1); __syncthreads(); }
  }

  const int rb = gbase + wv * 32;
  #pragma unroll
  for (int rt = 0; rt < 2; ++rt) {
    #pragma unroll
    for (int j = 0; j < 4; ++j) {
      int row = rb + rt * 16 + l4 * 4 + j;
      if (row < N) {
        float d = disv[row];
        size_t ro = ((size_t)row << 4) + l15;
        Y[0 * PLANE + ro] = bf16_rne(acc[rt][0][j] * d);
        Y[1 * PLANE + ro] = bf16_rne(acc[rt][1][j] * d);
        Y[2 * PLANE + ro] = bf16_rne(acc[rt][2][j] * d);
        Y[3 * PLANE + ro] = bf16_rne(acc[rt][3][j] * d);
      }
    }
  }
}

// ---------------- agg: plane-phased L2-resident gathers -------------------------------
// blockIdx plane-major (in-order dispatch -> co-resident blocks share one 3.2MB plane,
// which fits an XCD L2 -> gather lines become L2 hits instead of L3/fabric random
// access, the round-17-identified binder). Wave per (node,plane); g=lane>>3 edge slot,
// p=lane&7 ushort2 feature pair; 3-stage butterfly over slots.
__launch_bounds__(256)
__global__ void k_agg(const unsigned short* __restrict__ G, const int* __restrict__ offs,
                      const int* __restrict__ csr, const float* __restrict__ dis,
                      const float* __restrict__ bias, float* __restrict__ H, int N) {
  const int bid = blockIdx.x;
  const int q = bid / BPP;
  const int node = (bid - q * BPP) * 4 + (threadIdx.x >> 6);
  const int lane = threadIdx.x & 63;
  const int g = lane >> 3, p = lane & 7;
  const unsigned short* Gq = G + (size_t)q * PLANE;
  const int beg = offs[node], end = offs[node + 1];
  float ax = 0.f, ay = 0.f;
  int e = beg + g;
  for (; e + 24 < end; e += 32) {
    int s0 = csr[e], s1 = csr[e + 8], s2 = csr[e + 16], s3 = csr[e + 24];
    ushort2 v0 = *(const ushort2*)(Gq + ((size_t)s0 << 4) + (p << 1));
    ushort2 v1 = *(const ushort2*)(Gq + ((size_t)s1 << 4) + (p << 1));
    ushort2 v2 = *(const ushort2*)(Gq + ((size_t)s2 << 4) + (p << 1));
    ushort2 v3 = *(const ushort2*)(Gq + ((size_t)s3 << 4) + (p << 1));
    ax += bf16_f32(v0.x) + bf16_f32(v1.x) + bf16_f32(v2.x) + bf16_f32(v3.x);
    ay += bf16_f32(v0.y) + bf16_f32(v1.y) + bf16_f32(v2.y) + bf16_f32(v3.y);
  }
  for (; e < end; e += 8) {
    int s = csr[e];
    ushort2 v = *(const ushort2*)(Gq + ((size_t)s << 4) + (p << 1));
    ax += bf16_f32(v.x);
    ay += bf16_f32(v.y);
  }
  #pragma unroll
  for (int off = 8; off < 64; off <<= 1) {
    ax += __shfl_xor(ax, off, 64);
    ay += __shfl_xor(ay, off, 64);
  }
  if (g == 0) {
    ushort2 sv = *(const ushort2*)(Gq + ((size_t)node << 4) + (p << 1));
    float d = dis[node];
    float2 bq = ((const float2*)(bias + (q << 4)))[p];
    float ox = (ax + bf16_f32(sv.x)) * d + bq.x;
    float oy = (ay + bf16_f32(sv.y)) * d + bq.y;
    ox = (ox > 0.f) ? ox : SLOPE * ox;
    oy = (oy > 0.f) ? oy : SLOPE * oy;
    *(float2*)(H + ((size_t)node << 6) + (q << 4) + (p << 1)) = make_float2(ox, oy);
  }
}

// One wave per graph: mean-pool + fc1 + lrelu + fc2
__launch_bounds__(64)
__global__ void k_pool(const float* __restrict__ H, const int* __restrict__ batch,
                       const float* __restrict__ f1W, const float* __restrict__ f1b,
                       const float* __restrict__ f2W, const float* __restrict__ f2b,
                       float* __restrict__ out, int N) {
  int g = blockIdx.x;
  int lane = threadIdx.x;
  int lo = 0, hi = N;
  while (lo < hi) { int m = (lo + hi) >> 1; if (batch[m] < g) lo = m + 1; else hi = m; }
  int beg = lo;
  hi = N;
  while (lo < hi) { int m = (lo + hi) >> 1; if (batch[m] < g + 1) lo = m + 1; else hi = m; }
  int end = lo;
  float acc = 0.f;
  for (int r = beg; r < end; ++r) acc += H[(size_t)r * 64 + lane];
  float c = (float)(end - beg);
  acc /= (c < 1.f ? 1.f : c);
  __shared__ float p[64];
  p[lane] = acc;
  __syncthreads();
  float q = f1b[lane];
  #pragma unroll
  for (int k = 0; k < 64; ++k) q += p[k] * f1W[k * 64 + lane];
  q = (q > 0.f) ? q : SLOPE * q;
  float v = q * f2W[lane];
  #pragma unroll
  for (int off = 32; off > 0; off >>= 1) v += __shfl_down(v, off, 64);
  if (lane == 0) out[g] = v + f2b[0];
}

extern "C" void kernel_launch(void* const* d_in, const int* in_sizes, int n_in,
                              void* d_out, int out_size, void* d_ws, size_t ws_size,
                              hipStream_t stream) {
  const float* x    = (const float*)d_in[0];
  const int*  eidx  = (const int*)d_in[1];
  const int*  batch = (const int*)d_in[2];
  const float* W0 = (const float*)d_in[3];
  const float* b0 = (const float*)d_in[4];
  const float* W1 = (const float*)d_in[5];
  const float* b1 = (const float*)d_in[6];
  const float* W2 = (const float*)d_in[7];
  const float* b2 = (const float*)d_in[8];
  const float* f1W = (const float*)d_in[9];
  const float* f1b = (const float*)d_in[10];
  const float* f2W = (const float*)d_in[11];
  const float* f2b = (const float*)d_in[12];
  float* out = (float*)d_out;

  const int N = NN, E = NE;
  const int* src  = eidx;
  const int* dstp = eidx + E;

  char* w = (char*)d_ws;
  float* H     = (float*)w; w += (size_t)NPADC * 64 * 4;           // fp32 layer buffer
  unsigned short* G = (unsigned short*)w; w += (size_t)NPADC * 64 * 2;  // bf16 planes
  int*   csr   = (int*)w;   w += (size_t)E * 4;
  int*   offs  = (int*)w;   w += (size_t)(N + 4) * 4;
  float* dis   = (float*)w; w += (size_t)N * 4;
  int*   bh    = (int*)w;   w += (size_t)NBLK * NBUK * 4;
  int*   btot  = (int*)w;   w += (NBUK + 1) * 4;
  int*   boffs = (int*)w;   w += (NBUK + 4) * 4;
  short* wt0h  = (short*)w; w += 64 * 192 * 2;
  short* wt0l  = (short*)w; w += 64 * 192 * 2;
  short* wt1h  = (short*)w; w += 64 * 64 * 2;
  short* wt1l  = (short*)w; w += 64 * 64 * 2;
  short* wt2h  = (short*)w; w += 64 * 64 * 2;
  short* wt2l  = (short*)w; w += 64 * 64 * 2;
  unsigned* bedge = (unsigned*)H;   // bedge dead before first agg writes H

  k_wsplit<<<48, 256, 0, stream>>>(W0, wt0h, wt0l, NODE_IN, 192);
  k_wsplit<<<16, 256, 0, stream>>>(W1, wt1h, wt1l, 64, 64);
  k_wsplit<<<16, 256, 0, stream>>>(W2, wt2h, wt2l, 64, 64);

  k_hist<<<NBLK, 256, 0, stream>>>(dstp, bh, E);
  k_bucket_scan<<<NBUK, 256, 0, stream>>>(bh, btot);
  k_btot_scan<<<1, 512, 0, stream>>>(btot, boffs, E);
  k_scatter<<<NBLK, 256, 0, stream>>>(src, dstp, bh, boffs, bedge, E);
  k_b2csr<<<NBUK, 256, 0, stream>>>(bedge, boffs, offs, dis, csr, N);

  const int NTB = (N + 127) / 128;   // 782
  k_gemm<NODE_IN, 192><<<NTB, 256, 0, stream>>>(x, wt0h, wt0l, dis, G, N);
  k_agg<<<4 * BPP, 256, 0, stream>>>(G, offs, csr, dis, b0, H, N);
  k_gemm<64, 64><<<NTB, 256, 0, stream>>>(H, wt1h, wt1l, dis, G, N);
  k_agg<<<4 * BPP, 256, 0, stream>>>(G, offs, csr, dis, b1, H, N);
  k_gemm<64, 64><<<NTB, 256, 0, stream>>>(H, wt2h, wt2l, dis, G, N);
  k_agg<<<4 * BPP, 256, 0, stream>>>(G, offs, csr, dis, b2, H, N);
  k_pool<<<NG, 64, 0, stream>>>(H, batch, f1W, f1b, f2W, f2b, out, N);
}

// Round 19
// 308.693 us; speedup vs baseline: 1.8240x; 1.8240x over previous
//
#include <hip/hip_runtime.h>

#define NN 100000
#define NE 1600000
#define NG 1024
#define NODE_IN 163
#define SLOPE 0.01f
#define NBUK 391
#define BUKSH 8
#define EPB 8192
#define NBLK ((NE + EPB - 1) / EPB)

typedef short s16x8 __attribute__((ext_vector_type(8)));
typedef float f32x4 __attribute__((ext_vector_type(4)));

__device__ __forceinline__ unsigned short bf16_rne(float x) {
  unsigned u = __float_as_uint(x);
  return (unsigned short)((u + 0x7FFFu + ((u >> 16) & 1u)) >> 16);
}
__device__ __forceinline__ float bf16_f32(unsigned short h) {
  return __uint_as_float(((unsigned)h) << 16);
}

// ---------------- CSR build (privatized counting sort; rounds 4-14, verified) ---------
__global__ void k_hist(const int* __restrict__ dst, int* __restrict__ bh, int E) {
  __shared__ int h[NBUK];
  for (int i = threadIdx.x; i < NBUK; i += 256) h[i] = 0;
  __syncthreads();
  int beg = blockIdx.x * EPB, end = min(E, beg + EPB);
  for (int e = beg + threadIdx.x; e < end; e += 256) atomicAdd(&h[dst[e] >> BUKSH], 1);
  __syncthreads();
  for (int i = threadIdx.x; i < NBUK; i += 256) bh[blockIdx.x * NBUK + i] = h[i];
}

__global__ void k_bucket_scan(int* __restrict__ bh, int* __restrict__ btot) {
  __shared__ int s[256];
  int bucket = blockIdx.x, tid = threadIdx.x;
  int v = (tid < NBLK) ? bh[tid * NBUK + bucket] : 0;
  s[tid] = v;
  __syncthreads();
  for (int off = 1; off < 256; off <<= 1) {
    int t = (tid >= off) ? s[tid - off] : 0;
    __syncthreads();
    s[tid] += t;
    __syncthreads();
  }
  if (tid < NBLK) bh[tid * NBUK + bucket] = s[tid] - v;
  if (tid == 255) btot[bucket] = s[255];
}

__global__ void k_btot_scan(const int* __restrict__ btot, int* __restrict__ boffs, int E) {
  __shared__ int s[512];
  int tid = threadIdx.x;
  int v = (tid < NBUK) ? btot[tid] : 0;
  s[tid] = v;
  __syncthreads();
  for (int off = 1; off < 512; off <<= 1) {
    int t = (tid >= off) ? s[tid - off] : 0;
    __syncthreads();
    s[tid] += t;
    __syncthreads();
  }
  if (tid < NBUK) boffs[tid] = s[tid] - v;
  if (tid == 0) boffs[NBUK] = E;
}

__global__ void k_scatter(const int* __restrict__ src, const int* __restrict__ dst,
                          const int* __restrict__ bh, const int* __restrict__ boffs,
                          unsigned* __restrict__ bedge, int E) {
  __shared__ int cur[NBUK];
  for (int i = threadIdx.x; i < NBUK; i += 256)
    cur[i] = boffs[i] + bh[blockIdx.x * NBUK + i];
  __syncthreads();
  int beg = blockIdx.x * EPB, end = min(E, beg + EPB);
  for (int e = beg + threadIdx.x; e < end; e += 256) {
    int d = dst[e];
    int pos = atomicAdd(&cur[d >> BUKSH], 1);
    bedge[pos] = (unsigned)src[e] | ((unsigned)(d & 255) << 17);
  }
}

__global__ void k_b2csr(const unsigned* __restrict__ bedge, const int* __restrict__ boffs,
                        int* __restrict__ offs, float* __restrict__ dis,
                        int* __restrict__ csr, int N) {
  __shared__ int lcnt[256];
  __shared__ int s[256];
  __shared__ int lcur[256];
  int b = blockIdx.x, tid = threadIdx.x;
  int beg = boffs[b], end = boffs[b + 1];
  lcnt[tid] = 0;
  __syncthreads();
  for (int e = beg + tid; e < end; e += 256) atomicAdd(&lcnt[bedge[e] >> 17], 1);
  __syncthreads();
  int v = lcnt[tid];
  s[tid] = v;
  __syncthreads();
  for (int off = 1; off < 256; off <<= 1) {
    int t = (tid >= off) ? s[tid - off] : 0;
    __syncthreads();
    s[tid] += t;
    __syncthreads();
  }
  int o = s[tid] - v;
  int node = (b << BUKSH) + tid;
  if (node <= N) offs[node] = beg + o;
  if (node < N) dis[node] = rsqrtf((float)(v + 1));
  lcur[tid] = o;
  __syncthreads();
  for (int e = beg + tid; e < end; e += 256) {
    unsigned w = bedge[e];
    int p = atomicAdd(&lcur[w >> 17], 1);
    csr[beg + p] = (int)(w & 0x1FFFFu);
  }
}

// ---------------- W pre-split: W[K][64] fp32 -> Wt_hi/lo[64][KP] bf16 (transposed) ----
__global__ void k_wsplit(const float* __restrict__ W, short* __restrict__ hi,
                         short* __restrict__ lo, int K, int KP) {
  int idx = blockIdx.x * 256 + threadIdx.x;
  if (idx >= 64 * KP) return;
  int c = idx / KP, kk = idx - c * KP;
  float v = (kk < K) ? W[(size_t)kk * 64 + c] : 0.f;
  unsigned short h = bf16_rne(v);
  hi[idx] = (short)h;
  lo[idx] = (short)bf16_rne(v - bf16_f32(h));
}

// ---------------- GEMM via MFMA split-bf16 (round-14 proven: A+B staged in LDS) -------
template<int K, int KP>
__launch_bounds__(256)
__global__ void k_gemm(const float* __restrict__ X, const short* __restrict__ Whi,
                       const short* __restrict__ Wlo, const float* __restrict__ disv,
                       unsigned short* __restrict__ Y, int N) {
  constexpr int KC = KP / 32;
  constexpr int PA = 40;
  constexpr int PB = 40;
  __shared__ __align__(16) short sAh[2][128 * PA];
  __shared__ __align__(16) short sAl[2][128 * PA];
  __shared__ __align__(16) short sBh[2][64 * PB];
  __shared__ __align__(16) short sBl[2][64 * PB];

  const int tid = threadIdx.x;
  const int lane = tid & 63, wv = tid >> 6;
  const int l15 = lane & 15, l4 = lane >> 4;
  const int gbase = blockIdx.x << 7;

  const int arow = tid >> 1, akh = (tid & 1) << 4;
  int grow = gbase + arow;
  if (K != KP) grow = min(grow, N - 1);
  const float* xr = X + (size_t)grow * K;
  const int bcol = tid >> 2, bk8 = (tid & 3) << 3;

  float4 ra0, ra1, ra2, ra3;
  s16x8 rbh, rbl;

  auto loadA = [&](int c) {
    if (K != KP && c == KC - 1) {
      ra0 = ra1 = ra2 = ra3 = make_float4(0.f, 0.f, 0.f, 0.f);
      if (akh == 0) { ra0.x = xr[160]; ra0.y = xr[161]; ra0.z = xr[162]; }
    } else {
      const float* p = xr + c * 32 + akh;
      ra0 = *(const float4*)(p);
      ra1 = *(const float4*)(p + 4);
      ra2 = *(const float4*)(p + 8);
      ra3 = *(const float4*)(p + 12);
    }
  };
  auto loadB = [&](int c) {
    const size_t o = (size_t)bcol * KP + c * 32 + bk8;
    rbh = *(const s16x8*)(Whi + o);
    rbl = *(const s16x8*)(Wlo + o);
  };
  auto writeLDS = [&](int b) {
    short hb[16], lb[16];
    float v[16] = {ra0.x, ra0.y, ra0.z, ra0.w, ra1.x, ra1.y, ra1.z, ra1.w,
                   ra2.x, ra2.y, ra2.z, ra2.w, ra3.x, ra3.y, ra3.z, ra3.w};
    #pragma unroll
    for (int j = 0; j < 16; ++j) {
      unsigned short h = bf16_rne(v[j]);
      hb[j] = (short)h;
      lb[j] = (short)bf16_rne(v[j] - bf16_f32(h));
    }
    short* ah = sAh[b] + arow * PA + akh;
    *(s16x8*)(ah) = *(const s16x8*)(hb);
    *(s16x8*)(ah + 8) = *(const s16x8*)(hb + 8);
    short* al = sAl[b] + arow * PA + akh;
    *(s16x8*)(al) = *(const s16x8*)(lb);
    *(s16x8*)(al + 8) = *(const s16x8*)(lb + 8);
    *(s16x8*)(sBh[b] + bcol * PB + bk8) = rbh;
    *(s16x8*)(sBl[b] + bcol * PB + bk8) = rbl;
  };

  f32x4 acc[2][4];
  #pragma unroll
  for (int rt = 0; rt < 2; ++rt)
    #pragma unroll
    for (int ct = 0; ct < 4; ++ct) acc[rt][ct] = (f32x4){0.f, 0.f, 0.f, 0.f};

  loadA(0); loadB(0); writeLDS(0);
  __syncthreads();

  #pragma unroll 1
  for (int c = 0; c < KC; ++c) {
    if (c + 1 < KC) { loadA(c + 1); loadB(c + 1); }   // issue early (T14)
    const int b = c & 1;
    const int aoff0 = (wv * 32 + l15) * PA + l4 * 8;
    const int aoff1 = aoff0 + 16 * PA;
    s16x8 a0h = *(const s16x8*)(sAh[b] + aoff0);
    s16x8 a0l = *(const s16x8*)(sAl[b] + aoff0);
    s16x8 a1h = *(const s16x8*)(sAh[b] + aoff1);
    s16x8 a1l = *(const s16x8*)(sAl[b] + aoff1);
    #pragma unroll
    for (int ct = 0; ct < 4; ++ct) {
      const int boff = (ct * 16 + l15) * PB + l4 * 8;
      s16x8 bh = *(const s16x8*)(sBh[b] + boff);
      s16x8 bl = *(const s16x8*)(sBl[b] + boff);
      acc[0][ct] = __builtin_amdgcn_mfma_f32_16x16x32_bf16(a0h, bh, acc[0][ct], 0, 0, 0);
      acc[0][ct] = __builtin_amdgcn_mfma_f32_16x16x32_bf16(a0l, bh, acc[0][ct], 0, 0, 0);
      acc[0][ct] = __builtin_amdgcn_mfma_f32_16x16x32_bf16(a0h, bl, acc[0][ct], 0, 0, 0);
      acc[1][ct] = __builtin_amdgcn_mfma_f32_16x16x32_bf16(a1h, bh, acc[1][ct], 0, 0, 0);
      acc[1][ct] = __builtin_amdgcn_mfma_f32_16x16x32_bf16(a1l, bh, acc[1][ct], 0, 0, 0);
      acc[1][ct] = __builtin_amdgcn_mfma_f32_16x16x32_bf16(a1h, bl, acc[1][ct], 0, 0, 0);
    }
    if (c + 1 < KC) { writeLDS((c + 1) & 1); __syncthreads(); }
  }

  const int rb = gbase + wv * 32;
  #pragma unroll
  for (int rt = 0; rt < 2; ++rt) {
    #pragma unroll
    for (int j = 0; j < 4; ++j) {
      int row = rb + rt * 16 + l4 * 4 + j;
      if (row < N) {
        float d = disv[row];
        unsigned short* yp = Y + ((size_t)row << 6) + l15;
        yp[0]  = bf16_rne(acc[rt][0][j] * d);
        yp[16] = bf16_rne(acc[rt][1][j] * d);
        yp[32] = bf16_rne(acc[rt][2][j] * d);
        yp[48] = bf16_rne(acc[rt][3][j] * d);
      }
    }
  }
}

// ---------------- agg: quad-row gathers, 8 in flight (32 edges/iter) ------------------
// Wave per node. lane: g=lane>>4 (edge slot), p=lane&15 (feature quad).
// Round-17/18 model: FETCH = compulsory fabric traffic (0.86*|G|*8 XCDs, invariant);
// residual ~20us is issue/latency -> double outstanding quad-gathers 4 -> 8.
__launch_bounds__(256)
__global__ void k_agg(const unsigned short* __restrict__ G, const int* __restrict__ offs,
                      const int* __restrict__ csr, const float* __restrict__ dis,
                      const float* __restrict__ bias, float* __restrict__ H, int N) {
  int node = blockIdx.x * 4 + (threadIdx.x >> 6);
  if (node >= N) return;
  const int lane = threadIdx.x & 63;
  const int g = lane >> 4, p = lane & 15;
  const ushort4* G4 = (const ushort4*)G;     // 16 quads per row
  int beg = offs[node], end = offs[node + 1];
  float ax = 0.f, ay = 0.f, az = 0.f, aw = 0.f;
  int e = beg + g;
  for (; e + 28 < end; e += 32) {            // 8 edges for this slot, all valid
    int s0 = csr[e],      s1 = csr[e + 4],  s2 = csr[e + 8],  s3 = csr[e + 12];
    int s4 = csr[e + 16], s5 = csr[e + 20], s6 = csr[e + 24], s7 = csr[e + 28];
    ushort4 v0 = G4[(size_t)s0 * 16 + p];
    ushort4 v1 = G4[(size_t)s1 * 16 + p];
    ushort4 v2 = G4[(size_t)s2 * 16 + p];
    ushort4 v3 = G4[(size_t)s3 * 16 + p];
    ushort4 v4 = G4[(size_t)s4 * 16 + p];
    ushort4 v5 = G4[(size_t)s5 * 16 + p];
    ushort4 v6 = G4[(size_t)s6 * 16 + p];
    ushort4 v7 = G4[(size_t)s7 * 16 + p];
    ax += bf16_f32(v0.x) + bf16_f32(v1.x) + bf16_f32(v2.x) + bf16_f32(v3.x)
        + bf16_f32(v4.x) + bf16_f32(v5.x) + bf16_f32(v6.x) + bf16_f32(v7.x);
    ay += bf16_f32(v0.y) + bf16_f32(v1.y) + bf16_f32(v2.y) + bf16_f32(v3.y)
        + bf16_f32(v4.y) + bf16_f32(v5.y) + bf16_f32(v6.y) + bf16_f32(v7.y);
    az += bf16_f32(v0.z) + bf16_f32(v1.z) + bf16_f32(v2.z) + bf16_f32(v3.z)
        + bf16_f32(v4.z) + bf16_f32(v5.z) + bf16_f32(v6.z) + bf16_f32(v7.z);
    aw += bf16_f32(v0.w) + bf16_f32(v1.w) + bf16_f32(v2.w) + bf16_f32(v3.w)
        + bf16_f32(v4.w) + bf16_f32(v5.w) + bf16_f32(v6.w) + bf16_f32(v7.w);
  }
  for (; e + 12 < end; e += 16) {            // 4-deep batch
    int s0 = csr[e], s1 = csr[e + 4], s2 = csr[e + 8], s3 = csr[e + 12];
    ushort4 v0 = G4[(size_t)s0 * 16 + p];
    ushort4 v1 = G4[(size_t)s1 * 16 + p];
    ushort4 v2 = G4[(size_t)s2 * 16 + p];
    ushort4 v3 = G4[(size_t)s3 * 16 + p];
    ax += bf16_f32(v0.x) + bf16_f32(v1.x) + bf16_f32(v2.x) + bf16_f32(v3.x);
    ay += bf16_f32(v0.y) + bf16_f32(v1.y) + bf16_f32(v2.y) + bf16_f32(v3.y);
    az += bf16_f32(v0.z) + bf16_f32(v1.z) + bf16_f32(v2.z) + bf16_f32(v3.z);
    aw += bf16_f32(v0.w) + bf16_f32(v1.w) + bf16_f32(v2.w) + bf16_f32(v3.w);
  }
  for (; e < end; e += 4) {                  // per-slot tail, stride 4
    int s = csr[e];
    ushort4 v = G4[(size_t)s * 16 + p];
    ax += bf16_f32(v.x); ay += bf16_f32(v.y);
    az += bf16_f32(v.z); aw += bf16_f32(v.w);
  }
  // butterfly across the 4 slots (xor 16, 32)
  #pragma unroll
  for (int off = 16; off < 64; off <<= 1) {
    ax += __shfl_xor(ax, off, 64);
    ay += __shfl_xor(ay, off, 64);
    az += __shfl_xor(az, off, 64);
    aw += __shfl_xor(aw, off, 64);
  }
  if (g == 0) {                              // lanes 0-15: self + dis + bias + lrelu
    ushort4 sv = G4[(size_t)node * 16 + p];
    float d = dis[node];
    float4 bq = ((const float4*)bias)[p];
    float ox = (ax + bf16_f32(sv.x)) * d + bq.x;
    float oy = (ay + bf16_f32(sv.y)) * d + bq.y;
    float oz = (az + bf16_f32(sv.z)) * d + bq.z;
    float ow = (aw + bf16_f32(sv.w)) * d + bq.w;
    ox = (ox > 0.f) ? ox : SLOPE * ox;
    oy = (oy > 0.f) ? oy : SLOPE * oy;
    oz = (oz > 0.f) ? oz : SLOPE * oz;
    ow = (ow > 0.f) ? ow : SLOPE * ow;
    ((float4*)(H + ((size_t)node << 6)))[p] = make_float4(ox, oy, oz, ow);
  }
}

// One wave per graph: mean-pool + fc1 + lrelu + fc2
__launch_bounds__(64)
__global__ void k_pool(const float* __restrict__ H, const int* __restrict__ batch,
                       const float* __restrict__ f1W, const float* __restrict__ f1b,
                       const float* __restrict__ f2W, const float* __restrict__ f2b,
                       float* __restrict__ out, int N) {
  int g = blockIdx.x;
  int lane = threadIdx.x;
  int lo = 0, hi = N;
  while (lo < hi) { int m = (lo + hi) >> 1; if (batch[m] < g) lo = m + 1; else hi = m; }
  int beg = lo;
  hi = N;
  while (lo < hi) { int m = (lo + hi) >> 1; if (batch[m] < g + 1) lo = m + 1; else hi = m; }
  int end = lo;
  float acc = 0.f;
  for (int r = beg; r < end; ++r) acc += H[(size_t)r * 64 + lane];
  float c = (float)(end - beg);
  acc /= (c < 1.f ? 1.f : c);
  __shared__ float p[64];
  p[lane] = acc;
  __syncthreads();
  float q = f1b[lane];
  #pragma unroll
  for (int k = 0; k < 64; ++k) q += p[k] * f1W[k * 64 + lane];
  q = (q > 0.f) ? q : SLOPE * q;
  float v = q * f2W[lane];
  #pragma unroll
  for (int off = 32; off > 0; off >>= 1) v += __shfl_down(v, off, 64);
  if (lane == 0) out[g] = v + f2b[0];
}

extern "C" void kernel_launch(void* const* d_in, const int* in_sizes, int n_in,
                              void* d_out, int out_size, void* d_ws, size_t ws_size,
                              hipStream_t stream) {
  const float* x    = (const float*)d_in[0];
  const int*  eidx  = (const int*)d_in[1];
  const int*  batch = (const int*)d_in[2];
  const float* W0 = (const float*)d_in[3];
  const float* b0 = (const float*)d_in[4];
  const float* W1 = (const float*)d_in[5];
  const float* b1 = (const float*)d_in[6];
  const float* W2 = (const float*)d_in[7];
  const float* b2 = (const float*)d_in[8];
  const float* f1W = (const float*)d_in[9];
  const float* f1b = (const float*)d_in[10];
  const float* f2W = (const float*)d_in[11];
  const float* f2b = (const float*)d_in[12];
  float* out = (float*)d_out;

  const int N = NN, E = NE;
  const int* src  = eidx;
  const int* dstp = eidx + E;

  const size_t NPAD = 100096;   // 782*128 rows exactly
  char* w = (char*)d_ws;
  float* H     = (float*)w; w += NPAD * 64 * 4;                // fp32 layer buffer
  unsigned short* G = (unsigned short*)w; w += NPAD * 64 * 2;  // bf16 gemm output
  int*   csr   = (int*)w;   w += (size_t)E * 4;
  int*   offs  = (int*)w;   w += (size_t)(N + 4) * 4;
  float* dis   = (float*)w; w += (size_t)N * 4;
  int*   bh    = (int*)w;   w += (size_t)NBLK * NBUK * 4;
  int*   btot  = (int*)w;   w += (NBUK + 1) * 4;
  int*   boffs = (int*)w;   w += (NBUK + 4) * 4;
  short* wt0h  = (short*)w; w += 64 * 192 * 2;
  short* wt0l  = (short*)w; w += 64 * 192 * 2;
  short* wt1h  = (short*)w; w += 64 * 64 * 2;
  short* wt1l  = (short*)w; w += 64 * 64 * 2;
  short* wt2h  = (short*)w; w += 64 * 64 * 2;
  short* wt2l  = (short*)w; w += 64 * 64 * 2;
  unsigned* bedge = (unsigned*)H;   // bedge dead before first agg writes H

  k_wsplit<<<48, 256, 0, stream>>>(W0, wt0h, wt0l, NODE_IN, 192);
  k_wsplit<<<16, 256, 0, stream>>>(W1, wt1h, wt1l, 64, 64);
  k_wsplit<<<16, 256, 0, stream>>>(W2, wt2h, wt2l, 64, 64);

  k_hist<<<NBLK, 256, 0, stream>>>(dstp, bh, E);
  k_bucket_scan<<<NBUK, 256, 0, stream>>>(bh, btot);
  k_btot_scan<<<1, 512, 0, stream>>>(btot, boffs, E);
  k_scatter<<<NBLK, 256, 0, stream>>>(src, dstp, bh, boffs, bedge, E);
  k_b2csr<<<NBUK, 256, 0, stream>>>(bedge, boffs, offs, dis, csr, N);

  const int NTB = (N + 127) / 128;   // 782
  k_gemm<NODE_IN, 192><<<NTB, 256, 0, stream>>>(x, wt0h, wt0l, dis, G, N);
  k_agg<<<(N + 3) / 4, 256, 0, stream>>>(G, offs, csr, dis, b0, H, N);
  k_gemm<64, 64><<<NTB, 256, 0, stream>>>(H, wt1h, wt1l, dis, G, N);
  k_agg<<<(N + 3) / 4, 256, 0, stream>>>(G, offs, csr, dis, b1, H, N);
  k_gemm<64, 64><<<NTB, 256, 0, stream>>>(H, wt2h, wt2l, dis, G, N);
  k_agg<<<(N + 3) / 4, 256, 0, stream>>>(G, offs, csr, dis, b2, H, N);
  k_pool<<<NG, 64, 0, stream>>>(H, batch, f1W, f1b, f2W, f2b, out, N);
}